// Round 17
// baseline (204.928 us; speedup 1.0000x reference)
//
#include <hip/hip_runtime.h>
#include <hip/hip_bf16.h>
#include <hip/hip_fp16.h>
#include <stdint.h>

typedef __attribute__((ext_vector_type(8))) _Float16 f16x8;
typedef __attribute__((ext_vector_type(4))) float f32x4;

__device__ __forceinline__ void async16(void* lds, const void* g) {
  __builtin_amdgcn_global_load_lds(
      (const __attribute__((address_space(1))) void*)g,
      (__attribute__((address_space(3))) void*)lds, 16, 0, 0);
}

__device__ __forceinline__ uint16_t f2h_u(float f) {
  union { __half h; uint16_t u; } c;
  c.h = __float2half(f);  // v_cvt_f16_f32, RNE
  return c.u;
}

// ---- merged prep: x->fp16 (blocks 0..2047), Wqkv^T (2048..2815), Wproj^T (2816..3071) ----
__global__ __launch_bounds__(256)
void prep_all(const float* __restrict__ x, uint16_t* __restrict__ xh,
              const float* __restrict__ Wqkv, uint16_t* __restrict__ WqkvT,
              const float* __restrict__ Wproj, uint16_t* __restrict__ WpT) {
  const int bid = blockIdx.x;
  if (bid < 2048) {
    const int base = bid * 256 + threadIdx.x;
#pragma unroll
    for (int k = 0; k < 4; ++k) {
      const int i = base + k * 524288;
      float4 v = ((const float4*)x)[i];
      ushort4 o;
      o.x = f2h_u(v.x); o.y = f2h_u(v.y); o.z = f2h_u(v.z); o.w = f2h_u(v.w);
      ((ushort4*)xh)[i] = o;
    }
  } else {
    __shared__ float t[64][65];
    const float* in;
    uint16_t* out;
    int ldin, ldout, r0, c0;
    if (bid < 2816) {
      const int id = bid - 2048;
      in = Wqkv; out = WqkvT; ldin = 3072; ldout = 1024;
      c0 = (id % 48) * 64; r0 = (id / 48) * 64;
    } else {
      const int id = bid - 2816;
      in = Wproj; out = WpT; ldin = 1024; ldout = 1024;
      c0 = (id % 16) * 64; r0 = (id / 16) * 64;
    }
    const int tx = threadIdx.x & 63, ty = threadIdx.x >> 6;
#pragma unroll
    for (int i = 0; i < 16; ++i)
      t[ty + i * 4][tx] = in[(size_t)(r0 + ty + i * 4) * ldin + c0 + tx];
    __syncthreads();
#pragma unroll
    for (int i = 0; i < 16; ++i)
      out[(size_t)(c0 + ty + i * 4) * ldout + r0 + tx] = f2h_u(t[tx][ty + i * 4]);
  }
}

// ============ 8-PHASE f16 NT GEMM: 256x256, BK=64 (qk; best fetch economy at M=8192) ======
// EPI: 0 = qk writer (+bias; cols<1024 -> q, else k; row-major per batch)
template <int EPI>
__global__ __launch_bounds__(512, 2)
void gemm8p(const uint16_t* __restrict__ A, const uint16_t* __restrict__ B,
            void* __restrict__ Cv, void* __restrict__ Cv2,
            const float* __restrict__ bias,
            int nT, int lda, int ldb, int ldc,
            long long strA, long long strB, long long strC) {
  extern __shared__ uint16_t lds_u16[];  // 2 bufs x (Ah0,Ah1,Bh0,Bh1) x 16KB = 128 KB

  const int gx = gridDim.x, gy = gridDim.y;
  const int nwg = gx * gy * gridDim.z;
  const int fid = blockIdx.x + gx * (blockIdx.y + gy * blockIdx.z);
  const int fs = (fid & 7) * (nwg >> 3) + (fid >> 3);
  const int bx = fs % gx;
  const int by = (fs / gx) % gy;
  const int bz = fs / (gx * gy);

  const int tid = threadIdx.x;
  const int l = tid & 63;
  const int w = tid >> 6;
  const int wm = w >> 2, wn = w & 3;  // 2M x 4N
  const int l15 = l & 15, l4 = l >> 4;
  const int rowBase = bx * 256, colBase = by * 256;
  const uint16_t* Ag = A + (size_t)bz * strA;
  const uint16_t* Bg = B + (size_t)bz * strB;

  const uint16_t* sA[2][2];
  const uint16_t* sB[2][2];
#pragma unroll
  for (int u = 0; u < 2; ++u) {
    int c = tid + (u << 9);
    int cs = c ^ ((c >> 3) & 7);
    int row = cs >> 3, kc = (cs & 7) * 8;
    sA[0][u] = Ag + (size_t)(rowBase + row) * lda + kc;
    sA[1][u] = Ag + (size_t)(rowBase + 128 + row) * lda + kc;
    sB[0][u] = Bg + (size_t)(colBase + row) * ldb + kc;
    sB[1][u] = Bg + (size_t)(colBase + 128 + row) * ldb + kc;
  }

  f32x4 acc[8][4];
#pragma unroll
  for (int m = 0; m < 8; ++m)
#pragma unroll
    for (int n = 0; n < 4; ++n)
      acc[m][n] = (f32x4){0.f, 0.f, 0.f, 0.f};

#define SH_A(buf, h, koff)                                                     \
  {                                                                            \
    const uint32_t d_ = (buf)*32768u + (h)*8192u;                              \
    async16(&lds_u16[d_ + (size_t)tid * 8], sA[h][0] + (koff));                \
    async16(&lds_u16[d_ + (size_t)(tid + 512) * 8], sA[h][1] + (koff));        \
  }
#define SH_B(buf, h, koff)                                                     \
  {                                                                            \
    const uint32_t d_ = (buf)*32768u + 16384u + (h)*8192u;                     \
    async16(&lds_u16[d_ + (size_t)tid * 8], sB[h][0] + (koff));                \
    async16(&lds_u16[d_ + (size_t)(tid + 512) * 8], sB[h][1] + (koff));        \
  }
#define RD_A(dst, buf, mh)                                                     \
  _Pragma("unroll") for (int mr = 0; mr < 4; ++mr) {                           \
    const int lr = (mh)*64 + mr * 16 + l15;                                    \
    const char* hb = (const char*)lds_u16 + (buf)*65536 + wm * 16384;          \
    _Pragma("unroll") for (int ks = 0; ks < 2; ++ks)                           \
      dst[mr][ks] = *(const f16x8*)(hb + lr * 128 +                            \
                    ((ks * 64 + l4 * 16) ^ ((lr & 7) << 4)));                  \
  }
#define RD_B(dst, buf, nh)                                                     \
  _Pragma("unroll") for (int nr = 0; nr < 2; ++nr) {                           \
    const int lr = (wn & 1) * 64 + (nh)*32 + nr * 16 + l15;                    \
    const char* hb = (const char*)lds_u16 + (buf)*65536 + 32768 +              \
                     (wn >> 1) * 16384;                                        \
    _Pragma("unroll") for (int ks = 0; ks < 2; ++ks)                           \
      dst[nr][ks] = *(const f16x8*)(hb + lr * 128 +                            \
                    ((ks * 64 + l4 * 16) ^ ((lr & 7) << 4)));                  \
  }
#define MM(m0, n0, AF, BF)                                                     \
  __builtin_amdgcn_s_setprio(1);                                               \
  _Pragma("unroll") for (int ks = 0; ks < 2; ++ks)                             \
  _Pragma("unroll") for (int mr = 0; mr < 4; ++mr)                             \
  _Pragma("unroll") for (int nr = 0; nr < 2; ++nr)                             \
    acc[(m0) + mr][(n0) + nr] = __builtin_amdgcn_mfma_f32_16x16x32_f16(        \
        AF[mr][ks], BF[nr][ks], acc[(m0) + mr][(n0) + nr], 0, 0, 0);           \
  __builtin_amdgcn_s_setprio(0);
#define VMC(n) asm volatile("s_waitcnt vmcnt(" #n ")" ::: "memory");
#define BAR() __builtin_amdgcn_s_barrier();

  SH_A(0, 0, 0) SH_A(0, 1, 0) SH_B(0, 0, 0) SH_B(0, 1, 0)
  SH_B(1, 0, 64) SH_B(1, 1, 64)
  VMC(4)
  BAR()

  const int nIter = nT >> 1;
  for (int i = 0; i < nIter; ++i) {
    const int e2 = 2 * i + 2, o = 2 * i + 1, o2 = 2 * i + 3;
    const int ke2 = e2 << 6, ko = o << 6, ko2 = o2 << 6;
    f16x8 a0[4][2], a1[4][2], b0[2][2], b1[2][2];
    // ---- tile e (buf0) ----
    RD_A(a0, 0, 0) RD_B(b0, 0, 0)
    SH_A(1, 0, ko)
    BAR()
    MM(0, 0, a0, b0)
    RD_B(b1, 0, 1)
    SH_A(1, 1, ko)
    BAR()
    MM(0, 2, a0, b1)
    RD_A(a1, 0, 1)
    if (e2 < nT) SH_B(0, 0, ke2)
    BAR()
    MM(4, 2, a1, b1)
    if (e2 < nT) { SH_B(0, 1, ke2) VMC(4) } else { VMC(0) }
    BAR()
    MM(4, 0, a1, b0)
    // ---- tile o (buf1) ----
    RD_A(a0, 1, 0) RD_B(b0, 1, 0)
    if (e2 < nT) SH_A(0, 0, ke2)
    BAR()
    MM(0, 0, a0, b0)
    RD_B(b1, 1, 1)
    if (e2 < nT) SH_A(0, 1, ke2)
    BAR()
    MM(0, 2, a0, b1)
    RD_A(a1, 1, 1)
    if (o2 < nT) SH_B(1, 0, ko2)
    BAR()
    MM(4, 2, a1, b1)
    if (o2 < nT) { SH_B(1, 1, ko2) }
    if (i + 1 < nIter) { if (o2 < nT) { VMC(4) } else { VMC(0) } }
    BAR()
    MM(4, 0, a1, b0)
  }
#undef SH_A
#undef SH_B
#undef RD_A
#undef RD_B
#undef MM
#undef VMC
#undef BAR

  if (EPI == 0) {
    uint16_t* qd = (uint16_t*)Cv;
    uint16_t* kd = (uint16_t*)Cv2;
#pragma unroll
    for (int ni = 0; ni < 4; ++ni) {
      const int gcol = colBase + wn * 64 + ni * 16 + l15;
      const float bv = bias[gcol];
      uint16_t* base = (gcol < 1024 ? qd : kd) + (gcol & 1023);
#pragma unroll
      for (int mi = 0; mi < 8; ++mi)
#pragma unroll
        for (int j = 0; j < 4; ++j) {
          const int grow = rowBase + wm * 128 + mi * 16 + l4 * 4 + j;
          base[(size_t)(grow >> 11) * 2097152 + (size_t)(grow & 2047) * 1024] =
              f2h_u(acc[mi][ni][j] + bv);
        }
    }
  }
}

// ======== RING-3 f16 NT GEMM: 256x128, BK=64, 3 LDS slots, counted vmcnt(6) (logits) ========
// 8 waves as 4M x 2N, 64x64 out per wave. EPI 5: E=exp(sps)-writer + rowsum atomics.
template <int EPI>
__global__ __launch_bounds__(512, 2)
void gemm_r3(const uint16_t* __restrict__ A, const uint16_t* __restrict__ B,
             void* __restrict__ Cv, float* __restrict__ rowsum,
             int nT, int lda, int ldb, int ldc,
             long long strA, long long strB, long long strC) {
  extern __shared__ uint16_t lds_u16[];  // 3 slots x (A 256x64 + B 128x64) fp16 = 144 KB

  const int gx = gridDim.x, gy = gridDim.y;
  const int nwg = gx * gy * gridDim.z;
  const int fid = blockIdx.x + gx * (blockIdx.y + gy * blockIdx.z);
  const int fs = (fid & 7) * (nwg >> 3) + (fid >> 3);
  const int bx = fs % gx;
  const int by = (fs / gx) % gy;
  const int bz = fs / (gx * gy);

  const int tid = threadIdx.x;
  const int l = tid & 63;
  const int w = tid >> 6;
  const int wm = w >> 1, wn = w & 1;
  const int l15 = l & 15, l4 = l >> 4;
  const int rowBase = bx * 256, colBase = by * 128;
  const uint16_t* Ag = A + (size_t)bz * strA;
  const uint16_t* Bg = B + (size_t)bz * strB;

  const uint16_t* pA[4];
  const uint16_t* pB[2];
#pragma unroll
  for (int u = 0; u < 4; ++u) {
    int c = tid + (u << 9);
    int cs = c ^ ((c >> 3) & 7);
    pA[u] = Ag + (size_t)(rowBase + (cs >> 3)) * lda + (cs & 7) * 8;
  }
#pragma unroll
  for (int u = 0; u < 2; ++u) {
    int c = tid + (u << 9);
    int cs = c ^ ((c >> 3) & 7);
    pB[u] = Bg + (size_t)(colBase + (cs >> 3)) * ldb + (cs & 7) * 8;
  }

  f32x4 acc[4][4];
#pragma unroll
  for (int m = 0; m < 4; ++m)
#pragma unroll
    for (int n = 0; n < 4; ++n)
      acc[m][n] = (f32x4){0.f, 0.f, 0.f, 0.f};

#define STAGE(t2, s2)                                                          \
  {                                                                            \
    const int kb_ = (t2) << 6;                                                 \
    uint16_t* dA_ = lds_u16 + (s2) * 24576;                                    \
    uint16_t* dB_ = dA_ + 16384;                                               \
    _Pragma("unroll") for (int u = 0; u < 4; ++u)                              \
        async16(&dA_[(size_t)(tid + (u << 9)) * 8], pA[u] + kb_);              \
    _Pragma("unroll") for (int u = 0; u < 2; ++u)                              \
        async16(&dB_[(size_t)(tid + (u << 9)) * 8], pB[u] + kb_);              \
  }

  STAGE(0, 0)
  STAGE(1, 1)
  asm volatile("s_waitcnt vmcnt(6)" ::: "memory");
  __builtin_amdgcn_s_barrier();

  int sl = 0;
  for (int t = 0; t < nT; ++t) {
    int s2 = sl + 2; if (s2 >= 3) s2 -= 3;
    if (t + 2 < nT) STAGE(t + 2, s2)
    const uint16_t* As = lds_u16 + sl * 24576;
    const uint16_t* Bs = As + 16384;
#pragma unroll
    for (int ks = 0; ks < 2; ++ks) {
      f16x8 af[4], bf[4];
#pragma unroll
      for (int m = 0; m < 4; ++m) {
        const int r = wm * 64 + m * 16 + l15;
        const int byt = r * 128 + ((ks * 64 + l4 * 16) ^ ((r & 7) << 4));
        af[m] = *(const f16x8*)((const char*)As + byt);
      }
#pragma unroll
      for (int n = 0; n < 4; ++n) {
        const int r = wn * 64 + n * 16 + l15;
        const int byt = r * 128 + ((ks * 64 + l4 * 16) ^ ((r & 7) << 4));
        bf[n] = *(const f16x8*)((const char*)Bs + byt);
      }
      __builtin_amdgcn_s_setprio(1);
#pragma unroll
      for (int m = 0; m < 4; ++m)
#pragma unroll
        for (int n = 0; n < 4; ++n)
          acc[m][n] = __builtin_amdgcn_mfma_f32_16x16x32_f16(af[m], bf[n], acc[m][n], 0, 0, 0);
      __builtin_amdgcn_s_setprio(0);
    }
    if (t + 1 < nT) {
      if (t + 2 < nT) {
        asm volatile("s_waitcnt vmcnt(6)" ::: "memory");
      } else {
        asm volatile("s_waitcnt vmcnt(0)" ::: "memory");
      }
      __builtin_amdgcn_s_barrier();
    }
    sl = (sl == 2) ? 0 : sl + 1;
  }
#undef STAGE

  const int orow0 = rowBase + wm * 64 + l4 * 4;
  const int ocol0 = colBase + wn * 64 + l15;
  if (EPI == 5) {
    // E = exp(min(sps(xs),19) - 8) -> fp16 ; per-row partial sums -> atomicAdd rowsum
    uint16_t* C = (uint16_t*)Cv + (size_t)bz * strC;
    float* rs_b = rowsum + (size_t)bz * 2048;
#pragma unroll
    for (int m = 0; m < 4; ++m)
#pragma unroll
      for (int j = 0; j < 4; ++j) {
        const int grow = orow0 + m * 16 + j;
        float rs = 0.f;
#pragma unroll
        for (int n = 0; n < 4; ++n) {
          float xs = acc[m][n][j] * 0.125f;
          float mult = (xs > 2.94443897916644f) ? 2.0f
                     : (xs > 1.73460105538811f) ? 1.5f
                     : (xs < -2.19722457733622f) ? 0.1f
                     : (xs < -1.09861228866811f) ? 0.3f
                                                 : 1.0f;
          float e = __expf(fminf(xs * mult, 19.0f) - 8.0f);
          C[(size_t)grow * ldc + ocol0 + n * 16] = f2h_u(e);
          rs += e;
        }
        rs += __shfl_xor(rs, 1);
        rs += __shfl_xor(rs, 2);
        rs += __shfl_xor(rs, 4);
        rs += __shfl_xor(rs, 8);
        if (l15 == 0) atomicAdd(&rs_b[grow], rs);
      }
  }
}

// ============ MULTI-BLOCK f16 NT GEMM: 128x128, BK=64, dbuf 64KB -> 2 blocks/CU ============
// EPI: 2 = vT writer (bias by ROW, fp16) ; 4 = +bias->fp32 ; 6 = PV * 1/rowsum -> fp16
template <int EPI>
__global__ __launch_bounds__(256, 2)
void gemm_mb(const uint16_t* __restrict__ A, const uint16_t* __restrict__ B,
             void* __restrict__ Cv, const float* __restrict__ bias,
             float* __restrict__ rowsum,
             int nT, int lda, int ldb, int ldc,
             long long strA, long long strB, long long strC) {
  extern __shared__ uint16_t lds_u16[];  // 2 slots x (A 128x64 + B 128x64) = 64 KB

  const int gx = gridDim.x, gy = gridDim.y;
  const int nwg = gx * gy * gridDim.z;
  const int fid = blockIdx.x + gx * (blockIdx.y + gy * blockIdx.z);
  const int fs = (fid & 7) * (nwg >> 3) + (fid >> 3);
  const int bx = fs % gx;
  const int by = (fs / gx) % gy;
  const int bz = fs / (gx * gy);

  const int tid = threadIdx.x;
  const int l = tid & 63;
  const int w = tid >> 6;
  const int wm = w >> 1, wn = w & 1;
  const int l15 = l & 15, l4 = l >> 4;
  const int rowBase = bx * 128, colBase = by * 128;
  const uint16_t* Ag = A + (size_t)bz * strA;
  const uint16_t* Bg = B + (size_t)bz * strB;

  const uint16_t* pA[4];
  const uint16_t* pB[4];
#pragma unroll
  for (int u = 0; u < 4; ++u) {
    int c = tid + (u << 8);
    int cs = c ^ ((c >> 3) & 7);
    pA[u] = Ag + (size_t)(rowBase + (cs >> 3)) * lda + (cs & 7) * 8;
    pB[u] = Bg + (size_t)(colBase + (cs >> 3)) * ldb + (cs & 7) * 8;
  }

  f32x4 acc[4][4];
#pragma unroll
  for (int m = 0; m < 4; ++m)
#pragma unroll
    for (int n = 0; n < 4; ++n)
      acc[m][n] = (f32x4){0.f, 0.f, 0.f, 0.f};

#define STAGE(t2, s2)                                                          \
  {                                                                            \
    const int kb_ = (t2) << 6;                                                 \
    uint16_t* dA_ = lds_u16 + (s2)*16384;                                      \
    uint16_t* dB_ = dA_ + 8192;                                                \
    _Pragma("unroll") for (int u = 0; u < 4; ++u) {                            \
      async16(&dA_[(size_t)(tid + (u << 8)) * 8], pA[u] + kb_);                \
      async16(&dB_[(size_t)(tid + (u << 8)) * 8], pB[u] + kb_);                \
    }                                                                          \
  }

  STAGE(0, 0)
  asm volatile("s_waitcnt vmcnt(0)" ::: "memory");
  __builtin_amdgcn_s_barrier();

  for (int t = 0; t < nT; ++t) {
    const int s = t & 1;
    if (t + 1 < nT) STAGE(t + 1, s ^ 1)
    const uint16_t* As = lds_u16 + s * 16384;
    const uint16_t* Bs = As + 8192;
#pragma unroll
    for (int ks = 0; ks < 2; ++ks) {
      f16x8 af[4], bf[4];
#pragma unroll
      for (int m = 0; m < 4; ++m) {
        const int r = wm * 64 + m * 16 + l15;
        const int byt = r * 128 + ((ks * 64 + l4 * 16) ^ ((r & 7) << 4));
        af[m] = *(const f16x8*)((const char*)As + byt);
      }
#pragma unroll
      for (int n = 0; n < 4; ++n) {
        const int r = wn * 64 + n * 16 + l15;
        const int byt = r * 128 + ((ks * 64 + l4 * 16) ^ ((r & 7) << 4));
        bf[n] = *(const f16x8*)((const char*)Bs + byt);
      }
      __builtin_amdgcn_s_setprio(1);
#pragma unroll
      for (int m = 0; m < 4; ++m)
#pragma unroll
        for (int n = 0; n < 4; ++n)
          acc[m][n] = __builtin_amdgcn_mfma_f32_16x16x32_f16(af[m], bf[n], acc[m][n], 0, 0, 0);
      __builtin_amdgcn_s_setprio(0);
    }
    if (t + 1 < nT) {
      asm volatile("s_waitcnt vmcnt(0)" ::: "memory");
      __builtin_amdgcn_s_barrier();
    }
  }
#undef STAGE

  const int orow0 = rowBase + wm * 64 + l4 * 4;
  const int ocol0 = colBase + wn * 64 + l15;
  if (EPI == 2) {
    // vT writer: rows = v-dim d, cols = t ; bias indexed by ROW
    uint16_t* C = (uint16_t*)Cv + (size_t)bz * strC;
#pragma unroll
    for (int m = 0; m < 4; ++m)
#pragma unroll
      for (int j = 0; j < 4; ++j) {
        const int d = orow0 + m * 16 + j;
        const float bv = bias[d];
#pragma unroll
        for (int n = 0; n < 4; ++n)
          C[(size_t)d * ldc + ocol0 + n * 16] = f2h_u(acc[m][n][j] + bv);
      }
  } else if (EPI == 6) {
    // PV on E: out_row *= 1/rowsum[row] -> fp16
    uint16_t* C = (uint16_t*)Cv + (size_t)bz * strC;
    const float* rs_b = rowsum + (size_t)bz * 2048;
#pragma unroll
    for (int m = 0; m < 4; ++m)
#pragma unroll
      for (int j = 0; j < 4; ++j) {
        const int grow = orow0 + m * 16 + j;
        const float inv = 1.0f / rs_b[grow];
#pragma unroll
        for (int n = 0; n < 4; ++n)
          C[(size_t)grow * ldc + ocol0 + n * 16] = f2h_u(acc[m][n][j] * inv);
      }
  } else {
    float* C = (float*)Cv;
#pragma unroll
    for (int n = 0; n < 4; ++n) {
      const float bv = bias[ocol0 + n * 16];
#pragma unroll
      for (int m = 0; m < 4; ++m)
#pragma unroll
        for (int j = 0; j < 4; ++j)
          C[(size_t)(orow0 + m * 16 + j) * ldc + ocol0 + n * 16] = acc[m][n][j] + bv;
    }
  }
}

extern "C" void kernel_launch(void* const* d_in, const int* in_sizes, int n_in,
                              void* d_out, int out_size, void* d_ws, size_t ws_size,
                              hipStream_t stream) {
  const float* x     = (const float*)d_in[0];
  const float* Wqkv  = (const float*)d_in[1];
  const float* bqkv  = (const float*)d_in[2];
  const float* Wproj = (const float*)d_in[3];
  const float* bproj = (const float*)d_in[4];
  float* out = (float*)d_out;

  char* ws = (char*)d_ws;
  size_t off = 0;
  auto alloc = [&](size_t bytes) -> void* {
    void* p = ws + off;
    off += (bytes + 255) & ~(size_t)255;
    return p;
  };
  uint16_t* xh     = (uint16_t*)alloc(8192ULL * 1024 * 2);      // x fp16 [8192][1024]
  uint16_t* WqkvT  = (uint16_t*)alloc(3072ULL * 1024 * 2);      // Wqkv^T fp16 [3072][1024]
  uint16_t* WpT    = (uint16_t*)alloc(1024ULL * 1024 * 2);      // Wproj^T fp16
  uint16_t* qh     = (uint16_t*)alloc(4ULL * 2048 * 1024 * 2);  // q fp16 [b][t][d]
  uint16_t* kh     = (uint16_t*)alloc(4ULL * 2048 * 1024 * 2);  // k fp16 [b][t][d]
  uint16_t* vT     = (uint16_t*)alloc(4ULL * 1024 * 2048 * 2);  // v^T fp16 [b][d][t]
  uint16_t* Pm     = (uint16_t*)alloc(4ULL * 2048 * 2048 * 2);  // E = exp(sps-8) fp16
  float*    rowsum = (float*)alloc(4ULL * 2048 * 4);            // per-row sum of E
  uint16_t* ao     = xh;  // attn-out fp16 reuses xh (x dead after v GEMM)

  // 0. zero rowsum (atomic accumulation target)
  hipMemsetAsync(rowsum, 0, 4ULL * 2048 * 4, stream);
  // 1. merged prep: x->fp16, Wqkv^T, Wproj^T
  prep_all<<<3072, 256, 0, stream>>>(x, xh, Wqkv, WqkvT, Wproj, WpT);
  // 2. q,k = x@Wqk + b   (M=8192, N=2048, K=1024)  [8-phase 256x256]
  gemm8p<0><<<dim3(32, 8, 1), 512, 131072, stream>>>(
      xh, WqkvT, qh, kh, bqkv, 16, 1024, 1024, 0, 0, 0, 0);
  // 3. vT[b][d][t] = Wv^T @ x_b^T + bv[d]  (M=1024, N=2048/batch, K=1024)  [grid 512]
  gemm_mb<2><<<dim3(8, 16, 4), 256, 65536, stream>>>(
      WqkvT + 2048ULL * 1024, xh, vT, bqkv + 2048, nullptr,
      16, 1024, 1024, 2048, 0, 2097152LL, 2097152LL);
  // 4. E = exp(sps(q@k^T*0.125)-8), rowsum +=  (M=N=2048, K=1024, per batch)
  //    [ring-3 256x128 — round-5 measured 52.5 µs for this GEMM shape]
  gemm_r3<5><<<dim3(8, 16, 4), 512, 147456, stream>>>(
      qh, kh, Pm, rowsum, 16, 1024, 1024, 2048,
      2097152LL, 2097152LL, 4194304LL);
  // 5. attn_out = (E@V) / rowsum  (M=2048, N=1024, K=2048, per batch)  [grid 512]
  gemm_mb<6><<<dim3(16, 8, 4), 256, 65536, stream>>>(
      Pm, vT, ao, nullptr, rowsum, 32, 2048, 2048, 1024,
      4194304LL, 2097152LL, 2097152LL);
  // 6. out = ao@Wproj + b -> fp32  (M=8192, N=1024, K=1024)  [grid 512]
  gemm_mb<4><<<dim3(64, 8, 1), 256, 65536, stream>>>(
      ao, WpT, out, bproj, nullptr, 16, 1024, 1024, 1024, 0, 0, 0);
}

// Round 18
// 203.591 us; speedup vs baseline: 1.0066x; 1.0066x over previous
//
#include <hip/hip_runtime.h>
#include <hip/hip_bf16.h>
#include <hip/hip_fp16.h>
#include <stdint.h>

typedef __attribute__((ext_vector_type(8))) _Float16 f16x8;
typedef __attribute__((ext_vector_type(4))) float f32x4;

__device__ __forceinline__ void async16(void* lds, const void* g) {
  __builtin_amdgcn_global_load_lds(
      (const __attribute__((address_space(1))) void*)g,
      (__attribute__((address_space(3))) void*)lds, 16, 0, 0);
}

__device__ __forceinline__ uint16_t f2h_u(float f) {
  union { __half h; uint16_t u; } c;
  c.h = __float2half(f);  // v_cvt_f16_f32, RNE
  return c.u;
}

// ---- merged prep: x->fp16 (blocks 0..2047), Wqkv^T (2048..2815), Wproj^T (2816..3071) ----
__global__ __launch_bounds__(256)
void prep_all(const float* __restrict__ x, uint16_t* __restrict__ xh,
              const float* __restrict__ Wqkv, uint16_t* __restrict__ WqkvT,
              const float* __restrict__ Wproj, uint16_t* __restrict__ WpT) {
  const int bid = blockIdx.x;
  if (bid < 2048) {
    const int base = bid * 256 + threadIdx.x;
#pragma unroll
    for (int k = 0; k < 4; ++k) {
      const int i = base + k * 524288;
      float4 v = ((const float4*)x)[i];
      ushort4 o;
      o.x = f2h_u(v.x); o.y = f2h_u(v.y); o.z = f2h_u(v.z); o.w = f2h_u(v.w);
      ((ushort4*)xh)[i] = o;
    }
  } else {
    __shared__ float t[64][65];
    const float* in;
    uint16_t* out;
    int ldin, ldout, r0, c0;
    if (bid < 2816) {
      const int id = bid - 2048;
      in = Wqkv; out = WqkvT; ldin = 3072; ldout = 1024;
      c0 = (id % 48) * 64; r0 = (id / 48) * 64;
    } else {
      const int id = bid - 2816;
      in = Wproj; out = WpT; ldin = 1024; ldout = 1024;
      c0 = (id % 16) * 64; r0 = (id / 16) * 64;
    }
    const int tx = threadIdx.x & 63, ty = threadIdx.x >> 6;
#pragma unroll
    for (int i = 0; i < 16; ++i)
      t[ty + i * 4][tx] = in[(size_t)(r0 + ty + i * 4) * ldin + c0 + tx];
    __syncthreads();
#pragma unroll
    for (int i = 0; i < 16; ++i)
      out[(size_t)(c0 + ty + i * 4) * ldout + r0 + tx] = f2h_u(t[tx][ty + i * 4]);
  }
}

// ============ 8-PHASE f16 NT GEMM: 256x256, BK=64 (qk; best fetch economy at M=8192) ======
// EPI: 0 = qk writer (+bias; cols<1024 -> q, else k; row-major per batch)
template <int EPI>
__global__ __launch_bounds__(512, 2)
void gemm8p(const uint16_t* __restrict__ A, const uint16_t* __restrict__ B,
            void* __restrict__ Cv, void* __restrict__ Cv2,
            const float* __restrict__ bias,
            int nT, int lda, int ldb, int ldc,
            long long strA, long long strB, long long strC) {
  extern __shared__ uint16_t lds_u16[];  // 2 bufs x (Ah0,Ah1,Bh0,Bh1) x 16KB = 128 KB

  const int gx = gridDim.x, gy = gridDim.y;
  const int nwg = gx * gy * gridDim.z;
  const int fid = blockIdx.x + gx * (blockIdx.y + gy * blockIdx.z);
  const int fs = (fid & 7) * (nwg >> 3) + (fid >> 3);
  const int bx = fs % gx;
  const int by = (fs / gx) % gy;
  const int bz = fs / (gx * gy);

  const int tid = threadIdx.x;
  const int l = tid & 63;
  const int w = tid >> 6;
  const int wm = w >> 2, wn = w & 3;  // 2M x 4N
  const int l15 = l & 15, l4 = l >> 4;
  const int rowBase = bx * 256, colBase = by * 256;
  const uint16_t* Ag = A + (size_t)bz * strA;
  const uint16_t* Bg = B + (size_t)bz * strB;

  const uint16_t* sA[2][2];
  const uint16_t* sB[2][2];
#pragma unroll
  for (int u = 0; u < 2; ++u) {
    int c = tid + (u << 9);
    int cs = c ^ ((c >> 3) & 7);
    int row = cs >> 3, kc = (cs & 7) * 8;
    sA[0][u] = Ag + (size_t)(rowBase + row) * lda + kc;
    sA[1][u] = Ag + (size_t)(rowBase + 128 + row) * lda + kc;
    sB[0][u] = Bg + (size_t)(colBase + row) * ldb + kc;
    sB[1][u] = Bg + (size_t)(colBase + 128 + row) * ldb + kc;
  }

  f32x4 acc[8][4];
#pragma unroll
  for (int m = 0; m < 8; ++m)
#pragma unroll
    for (int n = 0; n < 4; ++n)
      acc[m][n] = (f32x4){0.f, 0.f, 0.f, 0.f};

#define SH_A(buf, h, koff)                                                     \
  {                                                                            \
    const uint32_t d_ = (buf)*32768u + (h)*8192u;                              \
    async16(&lds_u16[d_ + (size_t)tid * 8], sA[h][0] + (koff));                \
    async16(&lds_u16[d_ + (size_t)(tid + 512) * 8], sA[h][1] + (koff));        \
  }
#define SH_B(buf, h, koff)                                                     \
  {                                                                            \
    const uint32_t d_ = (buf)*32768u + 16384u + (h)*8192u;                     \
    async16(&lds_u16[d_ + (size_t)tid * 8], sB[h][0] + (koff));                \
    async16(&lds_u16[d_ + (size_t)(tid + 512) * 8], sB[h][1] + (koff));        \
  }
#define RD_A(dst, buf, mh)                                                     \
  _Pragma("unroll") for (int mr = 0; mr < 4; ++mr) {                           \
    const int lr = (mh)*64 + mr * 16 + l15;                                    \
    const char* hb = (const char*)lds_u16 + (buf)*65536 + wm * 16384;          \
    _Pragma("unroll") for (int ks = 0; ks < 2; ++ks)                           \
      dst[mr][ks] = *(const f16x8*)(hb + lr * 128 +                            \
                    ((ks * 64 + l4 * 16) ^ ((lr & 7) << 4)));                  \
  }
#define RD_B(dst, buf, nh)                                                     \
  _Pragma("unroll") for (int nr = 0; nr < 2; ++nr) {                           \
    const int lr = (wn & 1) * 64 + (nh)*32 + nr * 16 + l15;                    \
    const char* hb = (const char*)lds_u16 + (buf)*65536 + 32768 +              \
                     (wn >> 1) * 16384;                                        \
    _Pragma("unroll") for (int ks = 0; ks < 2; ++ks)                           \
      dst[nr][ks] = *(const f16x8*)(hb + lr * 128 +                            \
                    ((ks * 64 + l4 * 16) ^ ((lr & 7) << 4)));                  \
  }
#define MM(m0, n0, AF, BF)                                                     \
  __builtin_amdgcn_s_setprio(1);                                               \
  _Pragma("unroll") for (int ks = 0; ks < 2; ++ks)                             \
  _Pragma("unroll") for (int mr = 0; mr < 4; ++mr)                             \
  _Pragma("unroll") for (int nr = 0; nr < 2; ++nr)                             \
    acc[(m0) + mr][(n0) + nr] = __builtin_amdgcn_mfma_f32_16x16x32_f16(        \
        AF[mr][ks], BF[nr][ks], acc[(m0) + mr][(n0) + nr], 0, 0, 0);           \
  __builtin_amdgcn_s_setprio(0);
#define VMC(n) asm volatile("s_waitcnt vmcnt(" #n ")" ::: "memory");
#define BAR() __builtin_amdgcn_s_barrier();

  SH_A(0, 0, 0) SH_A(0, 1, 0) SH_B(0, 0, 0) SH_B(0, 1, 0)
  SH_B(1, 0, 64) SH_B(1, 1, 64)
  VMC(4)
  BAR()

  const int nIter = nT >> 1;
  for (int i = 0; i < nIter; ++i) {
    const int e2 = 2 * i + 2, o = 2 * i + 1, o2 = 2 * i + 3;
    const int ke2 = e2 << 6, ko = o << 6, ko2 = o2 << 6;
    f16x8 a0[4][2], a1[4][2], b0[2][2], b1[2][2];
    // ---- tile e (buf0) ----
    RD_A(a0, 0, 0) RD_B(b0, 0, 0)
    SH_A(1, 0, ko)
    BAR()
    MM(0, 0, a0, b0)
    RD_B(b1, 0, 1)
    SH_A(1, 1, ko)
    BAR()
    MM(0, 2, a0, b1)
    RD_A(a1, 0, 1)
    if (e2 < nT) SH_B(0, 0, ke2)
    BAR()
    MM(4, 2, a1, b1)
    if (e2 < nT) { SH_B(0, 1, ke2) VMC(4) } else { VMC(0) }
    BAR()
    MM(4, 0, a1, b0)
    // ---- tile o (buf1) ----
    RD_A(a0, 1, 0) RD_B(b0, 1, 0)
    if (e2 < nT) SH_A(0, 0, ke2)
    BAR()
    MM(0, 0, a0, b0)
    RD_B(b1, 1, 1)
    if (e2 < nT) SH_A(0, 1, ke2)
    BAR()
    MM(0, 2, a0, b1)
    RD_A(a1, 1, 1)
    if (o2 < nT) SH_B(1, 0, ko2)
    BAR()
    MM(4, 2, a1, b1)
    if (o2 < nT) { SH_B(1, 1, ko2) }
    if (i + 1 < nIter) { if (o2 < nT) { VMC(4) } else { VMC(0) } }
    BAR()
    MM(4, 0, a1, b0)
  }
#undef SH_A
#undef SH_B
#undef RD_A
#undef RD_B
#undef MM
#undef VMC
#undef BAR

  if (EPI == 0) {
    uint16_t* qd = (uint16_t*)Cv;
    uint16_t* kd = (uint16_t*)Cv2;
#pragma unroll
    for (int ni = 0; ni < 4; ++ni) {
      const int gcol = colBase + wn * 64 + ni * 16 + l15;
      const float bv = bias[gcol];
      uint16_t* base = (gcol < 1024 ? qd : kd) + (gcol & 1023);
#pragma unroll
      for (int mi = 0; mi < 8; ++mi)
#pragma unroll
        for (int j = 0; j < 4; ++j) {
          const int grow = rowBase + wm * 128 + mi * 16 + l4 * 4 + j;
          base[(size_t)(grow >> 11) * 2097152 + (size_t)(grow & 2047) * 1024] =
              f2h_u(acc[mi][ni][j] + bv);
        }
    }
  }
}

// ============ MULTI-BLOCK f16 NT GEMM: 128x128, BK=64, dbuf 64KB -> 2 blocks/CU ============
// EPI: 2 = vT writer (bias by ROW, fp16) ; 4 = +bias->fp32 ;
//      5 = E=exp(sps)-writer + rowsum atomics ; 6 = PV * 1/rowsum -> fp16
template <int EPI>
__global__ __launch_bounds__(256, 2)
void gemm_mb(const uint16_t* __restrict__ A, const uint16_t* __restrict__ B,
             void* __restrict__ Cv, const float* __restrict__ bias,
             float* __restrict__ rowsum,
             int nT, int lda, int ldb, int ldc,
             long long strA, long long strB, long long strC) {
  extern __shared__ uint16_t lds_u16[];  // 2 slots x (A 128x64 + B 128x64) = 64 KB

  const int gx = gridDim.x, gy = gridDim.y;
  const int nwg = gx * gy * gridDim.z;
  const int fid = blockIdx.x + gx * (blockIdx.y + gy * blockIdx.z);
  const int fs = (fid & 7) * (nwg >> 3) + (fid >> 3);
  const int bx = fs % gx;
  const int by = (fs / gx) % gy;
  const int bz = fs / (gx * gy);

  const int tid = threadIdx.x;
  const int l = tid & 63;
  const int w = tid >> 6;
  const int wm = w >> 1, wn = w & 1;
  const int l15 = l & 15, l4 = l >> 4;
  const int rowBase = bx * 128, colBase = by * 128;
  const uint16_t* Ag = A + (size_t)bz * strA;
  const uint16_t* Bg = B + (size_t)bz * strB;

  const uint16_t* pA[4];
  const uint16_t* pB[4];
#pragma unroll
  for (int u = 0; u < 4; ++u) {
    int c = tid + (u << 8);
    int cs = c ^ ((c >> 3) & 7);
    pA[u] = Ag + (size_t)(rowBase + (cs >> 3)) * lda + (cs & 7) * 8;
    pB[u] = Bg + (size_t)(colBase + (cs >> 3)) * ldb + (cs & 7) * 8;
  }

  f32x4 acc[4][4];
#pragma unroll
  for (int m = 0; m < 4; ++m)
#pragma unroll
    for (int n = 0; n < 4; ++n)
      acc[m][n] = (f32x4){0.f, 0.f, 0.f, 0.f};

#define STAGE(t2, s2)                                                          \
  {                                                                            \
    const int kb_ = (t2) << 6;                                                 \
    uint16_t* dA_ = lds_u16 + (s2)*16384;                                      \
    uint16_t* dB_ = dA_ + 8192;                                                \
    _Pragma("unroll") for (int u = 0; u < 4; ++u) {                            \
      async16(&dA_[(size_t)(tid + (u << 8)) * 8], pA[u] + kb_);                \
      async16(&dB_[(size_t)(tid + (u << 8)) * 8], pB[u] + kb_);                \
    }                                                                          \
  }

  STAGE(0, 0)
  asm volatile("s_waitcnt vmcnt(0)" ::: "memory");
  __builtin_amdgcn_s_barrier();

  for (int t = 0; t < nT; ++t) {
    const int s = t & 1;
    if (t + 1 < nT) STAGE(t + 1, s ^ 1)
    const uint16_t* As = lds_u16 + s * 16384;
    const uint16_t* Bs = As + 8192;
#pragma unroll
    for (int ks = 0; ks < 2; ++ks) {
      f16x8 af[4], bf[4];
#pragma unroll
      for (int m = 0; m < 4; ++m) {
        const int r = wm * 64 + m * 16 + l15;
        const int byt = r * 128 + ((ks * 64 + l4 * 16) ^ ((r & 7) << 4));
        af[m] = *(const f16x8*)((const char*)As + byt);
      }
#pragma unroll
      for (int n = 0; n < 4; ++n) {
        const int r = wn * 64 + n * 16 + l15;
        const int byt = r * 128 + ((ks * 64 + l4 * 16) ^ ((r & 7) << 4));
        bf[n] = *(const f16x8*)((const char*)Bs + byt);
      }
      __builtin_amdgcn_s_setprio(1);
#pragma unroll
      for (int m = 0; m < 4; ++m)
#pragma unroll
        for (int n = 0; n < 4; ++n)
          acc[m][n] = __builtin_amdgcn_mfma_f32_16x16x32_f16(af[m], bf[n], acc[m][n], 0, 0, 0);
      __builtin_amdgcn_s_setprio(0);
    }
    if (t + 1 < nT) {
      asm volatile("s_waitcnt vmcnt(0)" ::: "memory");
      __builtin_amdgcn_s_barrier();
    }
  }
#undef STAGE

  const int orow0 = rowBase + wm * 64 + l4 * 4;
  const int ocol0 = colBase + wn * 64 + l15;
  if (EPI == 2) {
    // vT writer: rows = v-dim d, cols = t ; bias indexed by ROW
    uint16_t* C = (uint16_t*)Cv + (size_t)bz * strC;
#pragma unroll
    for (int m = 0; m < 4; ++m)
#pragma unroll
      for (int j = 0; j < 4; ++j) {
        const int d = orow0 + m * 16 + j;
        const float bv = bias[d];
#pragma unroll
        for (int n = 0; n < 4; ++n)
          C[(size_t)d * ldc + ocol0 + n * 16] = f2h_u(acc[m][n][j] + bv);
      }
  } else if (EPI == 5) {
    // E = exp(min(sps(xs),19) - 8) -> fp16 ; per-row partial sums -> atomicAdd rowsum
    uint16_t* C = (uint16_t*)Cv + (size_t)bz * strC;
    float* rs_b = rowsum + (size_t)bz * 2048;
#pragma unroll
    for (int m = 0; m < 4; ++m)
#pragma unroll
      for (int j = 0; j < 4; ++j) {
        const int grow = orow0 + m * 16 + j;
        float rs = 0.f;
#pragma unroll
        for (int n = 0; n < 4; ++n) {
          float xs = acc[m][n][j] * 0.125f;
          float mult = (xs > 2.94443897916644f) ? 2.0f
                     : (xs > 1.73460105538811f) ? 1.5f
                     : (xs < -2.19722457733622f) ? 0.1f
                     : (xs < -1.09861228866811f) ? 0.3f
                                                 : 1.0f;
          float e = __expf(fminf(xs * mult, 19.0f) - 8.0f);
          C[(size_t)grow * ldc + ocol0 + n * 16] = f2h_u(e);
          rs += e;
        }
        rs += __shfl_xor(rs, 1);
        rs += __shfl_xor(rs, 2);
        rs += __shfl_xor(rs, 4);
        rs += __shfl_xor(rs, 8);
        if (l15 == 0) atomicAdd(&rs_b[grow], rs);
      }
  } else if (EPI == 6) {
    // PV on E: out_row *= 1/rowsum[row] -> fp16
    uint16_t* C = (uint16_t*)Cv + (size_t)bz * strC;
    const float* rs_b = rowsum + (size_t)bz * 2048;
#pragma unroll
    for (int m = 0; m < 4; ++m)
#pragma unroll
      for (int j = 0; j < 4; ++j) {
        const int grow = orow0 + m * 16 + j;
        const float inv = 1.0f / rs_b[grow];
#pragma unroll
        for (int n = 0; n < 4; ++n)
          C[(size_t)grow * ldc + ocol0 + n * 16] = f2h_u(acc[m][n][j] * inv);
      }
  } else {
    float* C = (float*)Cv;
#pragma unroll
    for (int n = 0; n < 4; ++n) {
      const float bv = bias[ocol0 + n * 16];
#pragma unroll
      for (int m = 0; m < 4; ++m)
#pragma unroll
        for (int j = 0; j < 4; ++j)
          C[(size_t)(orow0 + m * 16 + j) * ldc + ocol0 + n * 16] = acc[m][n][j] + bv;
    }
  }
}

extern "C" void kernel_launch(void* const* d_in, const int* in_sizes, int n_in,
                              void* d_out, int out_size, void* d_ws, size_t ws_size,
                              hipStream_t stream) {
  const float* x     = (const float*)d_in[0];
  const float* Wqkv  = (const float*)d_in[1];
  const float* bqkv  = (const float*)d_in[2];
  const float* Wproj = (const float*)d_in[3];
  const float* bproj = (const float*)d_in[4];
  float* out = (float*)d_out;

  char* ws = (char*)d_ws;
  size_t off = 0;
  auto alloc = [&](size_t bytes) -> void* {
    void* p = ws + off;
    off += (bytes + 255) & ~(size_t)255;
    return p;
  };
  uint16_t* xh     = (uint16_t*)alloc(8192ULL * 1024 * 2);      // x fp16 [8192][1024]
  uint16_t* WqkvT  = (uint16_t*)alloc(3072ULL * 1024 * 2);      // Wqkv^T fp16 [3072][1024]
  uint16_t* WpT    = (uint16_t*)alloc(1024ULL * 1024 * 2);      // Wproj^T fp16
  uint16_t* qh     = (uint16_t*)alloc(4ULL * 2048 * 1024 * 2);  // q fp16 [b][t][d]
  uint16_t* kh     = (uint16_t*)alloc(4ULL * 2048 * 1024 * 2);  // k fp16 [b][t][d]
  uint16_t* vT     = (uint16_t*)alloc(4ULL * 1024 * 2048 * 2);  // v^T fp16 [b][d][t]
  uint16_t* Pm     = (uint16_t*)alloc(4ULL * 2048 * 2048 * 2);  // E = exp(sps-8) fp16
  float*    rowsum = (float*)alloc(4ULL * 2048 * 4);            // per-row sum of E
  uint16_t* ao     = xh;  // attn-out fp16 reuses xh (x dead after v GEMM)

  // 0. zero rowsum (atomic accumulation target)
  hipMemsetAsync(rowsum, 0, 4ULL * 2048 * 4, stream);
  // 1. merged prep: x->fp16, Wqkv^T, Wproj^T
  prep_all<<<3072, 256, 0, stream>>>(x, xh, Wqkv, WqkvT, Wproj, WpT);
  // 2. q,k = x@Wqk + b   (M=8192, N=2048, K=1024)  [8-phase 256x256 — best fetch economy]
  gemm8p<0><<<dim3(32, 8, 1), 512, 131072, stream>>>(
      xh, WqkvT, qh, kh, bqkv, 16, 1024, 1024, 0, 0, 0, 0);
  // 3. vT[b][d][t] = Wv^T @ x_b^T + bv[d]  (M=1024, N=2048/batch, K=1024)  [grid 512]
  gemm_mb<2><<<dim3(8, 16, 4), 256, 65536, stream>>>(
      WqkvT + 2048ULL * 1024, xh, vT, bqkv + 2048, nullptr,
      16, 1024, 1024, 2048, 0, 2097152LL, 2097152LL);
  // 4. E = exp(sps(q@k^T*0.125)-8), rowsum += (M=N=2048, K=1024, per batch)  [grid 1024]
  gemm_mb<5><<<dim3(16, 16, 4), 256, 65536, stream>>>(
      qh, kh, Pm, nullptr, rowsum, 16, 1024, 1024, 2048,
      2097152LL, 2097152LL, 4194304LL);
  // 5. attn_out = (E@V) / rowsum  (M=2048, N=1024, K=2048, per batch)  [grid 512]
  gemm_mb<6><<<dim3(16, 8, 4), 256, 65536, stream>>>(
      Pm, vT, ao, nullptr, rowsum, 32, 2048, 2048, 1024,
      4194304LL, 2097152LL, 2097152LL);
  // 6. out = ao@Wproj + b -> fp32  (M=8192, N=1024, K=1024)  [grid 512]
  gemm_mb<4><<<dim3(64, 8, 1), 256, 65536, stream>>>(
      ao, WpT, out, bproj, nullptr, 16, 1024, 1024, 1024, 0, 0, 0);
}